// Round 9
// baseline (312.225 us; speedup 1.0000x reference)
//
#include <hip/hip_runtime.h>
#include <hip/hip_bf16.h>

// Problem constants
#define B_  128
#define T_  512
#define D_  400
#define NV  1024
#define NA  128

// Main kernel: r8 base (16 v/wave, 64 v/block, 3 blocks/CU, swizzled Hbf DMA)
// with the tile loop restructured into 3 fine phases (T3-style):
//   phase p: { stage-slice p of next tile | ds_read cluster | setprio MFMA | s_barrier }
// and a single vmcnt(0)+barrier at tile end. Defer-max (T13) in the softmax.
#define LDH  416
#define NT   32
#define MV   64
#define LOG2E 1.4426950408889634f

typedef __bf16 bf16_t;
typedef bf16_t bf16x8 __attribute__((ext_vector_type(8)));
typedef float  floatx4 __attribute__((ext_vector_type(4)));

__device__ inline void async_copy16(const void* g, void* l) {
    __builtin_amdgcn_global_load_lds(
        (const __attribute__((address_space(1))) unsigned int*)g,
        (__attribute__((address_space(3))) unsigned int*)l, 16, 0, 0);
}

__device__ inline float dot4(float4 a, float4 b) {
    return a.x * b.x + a.y * b.y + a.z * b.z + a.w * b.w;
}

// ---------------------------------------------------------------------------
// prep kernel (r8-verbatim), grid = 128 + 2048 blocks:
//   blocks [0,128)    : qacts (s2 + softmax + q_acts -> q_ws)
//   blocks [128,2176) : hw + swizzled Hbf, eight rows per wave.
// ---------------------------------------------------------------------------
template<int PRE>
__global__ __launch_bounds__(256) void prep_kernel(const float* __restrict__ H,
                                                   const float* __restrict__ W,
                                                   const float* __restrict__ cu,
                                                   const float* __restrict__ Ca,
                                                   float* __restrict__ hw,
                                                   bf16_t* __restrict__ Hbf,
                                                   float* __restrict__ q_ws) {
    __shared__ __align__(16) float4 cu4[100];
    __shared__ float s_lds[NA];
    __shared__ float p_lds[NA];
    __shared__ float red[8];
    __shared__ __align__(16) float4 part[100];

    int tid = threadIdx.x, wave = tid >> 6, lane = tid & 63;

    if (blockIdx.x >= 128) {
        long wid = (long)(blockIdx.x - 128) * 4 + wave;   // [0, 8192)
        long r0 = wid * 8;
        const float* base = H + r0 * D_;
        float acc[8];
#pragma unroll
        for (int j = 0; j < 8; ++j) acc[j] = 0.f;

        if (lane < 50) {
            float4 wx = ((const float4*)W)[lane * 2];
            float4 wy = ((const float4*)W)[lane * 2 + 1];
            bf16_t* ob = Hbf + r0 * (long)LDH;
#pragma unroll
            for (int j = 0; j < 8; ++j) {
                const float4* p = (const float4*)(base + (long)j * D_ + lane * 8);
                float4 x = p[0], y = p[1];
                acc[j] = dot4(x, wx) + dot4(y, wy);
                if (PRE) {
                    bf16x8 f;
                    f[0] = (bf16_t)x.x; f[1] = (bf16_t)x.y;
                    f[2] = (bf16_t)x.z; f[3] = (bf16_t)x.w;
                    f[4] = (bf16_t)y.x; f[5] = (bf16_t)y.y;
                    f[6] = (bf16_t)y.z; f[7] = (bf16_t)y.w;
                    int pj = (lane < 48) ? (lane ^ j) : lane;   // key = (r0+j)&7 = j
                    *(bf16x8*)(ob + (long)j * LDH + pj * 8) = f;
                }
            }
        } else if (PRE && lane < 52) {
            bf16x8 z;
#pragma unroll
            for (int jj = 0; jj < 8; ++jj) z[jj] = (bf16_t)0.0f;
            bf16_t* ob = Hbf + r0 * (long)LDH + lane * 8;
#pragma unroll
            for (int j = 0; j < 8; ++j)
                *(bf16x8*)(ob + (long)j * LDH) = z;
        }

#pragma unroll
        for (int off = 1; off < 64; off <<= 1) {
#pragma unroll
            for (int j = 0; j < 8; ++j) acc[j] += __shfl_xor(acc[j], off, 64);
        }
        if (lane == 0) {
#pragma unroll
            for (int j = 0; j < 8; ++j) hw[r0 + j] = acc[j];
        }
        return;
    }

    int b = blockIdx.x;

    if (tid < 100) cu4[tid] = ((const float4*)(cu + (size_t)b * D_))[tid];
    __syncthreads();

    const float4* Cb4 = (const float4*)(Ca + (size_t)b * NA * D_);
#pragma unroll 2
    for (int i = 0; i < 32; ++i) {
        int a = wave * 32 + i;
        const float4* row = Cb4 + (size_t)a * 100;
        float acc = dot4(row[lane], cu4[lane]);
        if (lane < 36) acc += dot4(row[lane + 64], cu4[lane + 64]);
#pragma unroll
        for (int off = 1; off < 64; off <<= 1) acc += __shfl_xor(acc, off, 64);
        if (lane == 0) s_lds[a] = acc;
    }
    __syncthreads();

    float s = (tid < NA) ? s_lds[tid] : -3.0e38f;
    float m = s;
#pragma unroll
    for (int off = 1; off < 64; off <<= 1) m = fmaxf(m, __shfl_xor(m, off, 64));
    if (lane == 0) red[wave] = m;
    __syncthreads();
    m = fmaxf(red[0], red[1]);
    float e = (tid < NA) ? __expf(s - m) : 0.f;
    float sum = e;
#pragma unroll
    for (int off = 1; off < 64; off <<= 1) sum += __shfl_xor(sum, off, 64);
    if (lane == 0) red[4 + wave] = sum;
    __syncthreads();
    float S = red[4] + red[5];
    if (tid < NA) p_lds[tid] = e / S;
    __syncthreads();

    int c4 = tid % 100;
    int half = tid / 100;
    float4 acc0 = {0.f, 0.f, 0.f, 0.f};
    if (tid < 200) {
        float4 acc1 = {0.f, 0.f, 0.f, 0.f};
        int a0 = half * 64;
#pragma unroll 4
        for (int a = 0; a < 64; a += 2) {
            float p0 = p_lds[a0 + a], p1 = p_lds[a0 + a + 1];
            float4 x0 = Cb4[(size_t)(a0 + a) * 100 + c4];
            float4 x1 = Cb4[(size_t)(a0 + a + 1) * 100 + c4];
            acc0.x += p0 * x0.x; acc0.y += p0 * x0.y; acc0.z += p0 * x0.z; acc0.w += p0 * x0.w;
            acc1.x += p1 * x1.x; acc1.y += p1 * x1.y; acc1.z += p1 * x1.z; acc1.w += p1 * x1.w;
        }
        acc0.x += acc1.x; acc0.y += acc1.y; acc0.z += acc1.z; acc0.w += acc1.w;
        if (half == 1) part[c4] = acc0;
    }
    __syncthreads();
    if (tid < 100) {
        float4 o = part[c4];
        o.x += acc0.x; o.y += acc0.y; o.z += acc0.z; o.w += acc0.w;
        ((float4*)(q_ws + (size_t)b * D_))[c4] = o;
    }
}

// ---------------------------------------------------------------------------
// Main kernel: 3-phase fine-interleaved tile loop (PRE=1).
// ---------------------------------------------------------------------------
template<int PRE>
__global__ __launch_bounds__(256, 3) void main_kernel(const float* __restrict__ H,
                                                      const bf16_t* __restrict__ Hbf,
                                                      const float* __restrict__ Cv,
                                                      const float* __restrict__ hw,
                                                      const float* __restrict__ q_ws,
                                                      const float* __restrict__ bs,
                                                      const int* __restrict__ lens,
                                                      float* __restrict__ out) {
    __shared__ bf16_t h_lds[2][NT * LDH];   // 53,248 B -> 3 blocks/CU

    int i = blockIdx.x;
    int xcd = i & 7, vc = (i >> 3) & 15, bb = i >> 7;
    int b = xcd + 8 * bb;
    int vbase = vc * MV;

    int tid = threadIdx.x;
    int wave = tid >> 6, lane = tid & 63;
    int lrow = lane & 15, quad = lane >> 4;

    int len = lens[b];
    float b0 = bs[0];

    if (!PRE) {
        for (int idx = tid; idx < 2 * NT * 2; idx += 256) {
            int bu = idx >> 6, rem = idx & 63;
            int r = rem >> 1, c = 50 + (rem & 1);
            bf16x8 z;
#pragma unroll
            for (int j = 0; j < 8; ++j) z[j] = (bf16_t)0.0f;
            *(bf16x8*)((char*)h_lds[bu] + r * 832 + c * 16) = z;
        }
    }

    // A fragments: this wave's 16 Cv rows, scaled by log2e, stationary
    bf16x8 afrag[13];
    {
        const float* vrow = Cv + (size_t)(vbase + wave * 16 + lrow) * D_;
#pragma unroll
        for (int kk = 0; kk < 13; ++kk) {
            int k0 = kk * 32 + quad * 8;
            bf16x8 f;
            if (k0 >= D_) {
#pragma unroll
                for (int j = 0; j < 8; ++j) f[j] = (bf16_t)0.0f;
            } else {
                const float4* p = (const float4*)(vrow + k0);
                float4 x = p[0], y = p[1];
                f[0] = (bf16_t)(x.x * LOG2E); f[1] = (bf16_t)(x.y * LOG2E);
                f[2] = (bf16_t)(x.z * LOG2E); f[3] = (bf16_t)(x.w * LOG2E);
                f[4] = (bf16_t)(y.x * LOG2E); f[5] = (bf16_t)(y.y * LOG2E);
                f[6] = (bf16_t)(y.z * LOG2E); f[7] = (bf16_t)(y.w * LOG2E);
            }
            afrag[kk] = f;
        }
    }

    float m_s[4], l_s[4], a_s[4];
#pragma unroll
    for (int r = 0; r < 4; ++r) { m_s[r] = -3.0e38f; l_s[r] = 0.f; a_s[r] = 0.f; }

    int ntiles = (len + NT - 1) / NT;
    const float* Hb = H + (size_t)b * T_ * D_;
    const bf16_t* Hbfb = Hbf + (size_t)b * T_ * LDH;
    const float* hwb = hw + (size_t)b * T_;

    // stage slice: issues for k-chunk indices [k0,k1) (7 total, split 3/2/2)
    auto stage_part = [&](int buf, int tt, int k0, int k1) {
        const char* gt = (const char*)(Hbfb + (size_t)tt * NT * LDH);
        char* lt = (char*)h_lds[buf];
        int cbase = wave * 416 + lane;
#pragma unroll
        for (int k = k0; k < k1; ++k) {
            int c = cbase + (k << 6);
            if (lane + (k << 6) < 416)
                async_copy16(gt + c * 16, lt + c * 16);
        }
    };

    auto stage_f32 = [&](int buf, int tt) {
        for (int idx = tid; idx < NT * 50; idx += 256) {
            int r = idx / 50, c = idx - r * 50;
            const float4* s = (const float4*)(Hb + (size_t)(tt * NT + r) * D_ + c * 8);
            float4 x = s[0], y = s[1];
            bf16x8 f;
            f[0] = (bf16_t)x.x; f[1] = (bf16_t)x.y; f[2] = (bf16_t)x.z; f[3] = (bf16_t)x.w;
            f[4] = (bf16_t)y.x; f[5] = (bf16_t)y.y; f[6] = (bf16_t)y.z; f[7] = (bf16_t)y.w;
            int pos = (c < 48) ? (c ^ (r & 7)) : c;
            *(bf16x8*)((char*)h_lds[buf] + r * 832 + pos * 16) = f;
        }
    };

    // prologue: fill buffer 0
    if (PRE) {
        stage_part(0, 0, 0, 7);
        asm volatile("s_waitcnt vmcnt(0)" ::: "memory");
        __builtin_amdgcn_s_barrier();
    } else {
        stage_f32(0, 0);
        __syncthreads();
    }

    const int swz = (lrow & 7) << 4;
    const int rowb0 = lrow * 832;
    const int rowb1 = (16 + lrow) * 832;

    for (int tt = 0; tt < ntiles; ++tt) {
        int cur = tt & 1;
        bool pre_next = (tt + 1 < ntiles);
        const char* L = (const char*)h_lds[cur];

        floatx4 c0 = {0.f, 0.f, 0.f, 0.f};
        floatx4 c1 = {0.f, 0.f, 0.f, 0.f};

        if (PRE) {
            // ---- phase 0: kk 0-3, stage slice {0,1,2} ----
            if (pre_next) stage_part(cur ^ 1, tt + 1, 0, 3);
            __builtin_amdgcn_s_setprio(1);
#pragma unroll
            for (int kk = 0; kk < 4; ++kk) {
                int o = (kk * 64 + quad * 16) ^ swz;
                bf16x8 f0 = *(const bf16x8*)(L + rowb0 + o);
                c0 = __builtin_amdgcn_mfma_f32_16x16x32_bf16(afrag[kk], f0, c0, 0, 0, 0);
                bf16x8 f1 = *(const bf16x8*)(L + rowb1 + o);
                c1 = __builtin_amdgcn_mfma_f32_16x16x32_bf16(afrag[kk], f1, c1, 0, 0, 0);
            }
            __builtin_amdgcn_s_setprio(0);
            __builtin_amdgcn_s_barrier();

            // ---- phase 1: kk 4-7, stage slice {3,4} ----
            if (pre_next) stage_part(cur ^ 1, tt + 1, 3, 5);
            __builtin_amdgcn_s_setprio(1);
#pragma unroll
            for (int kk = 4; kk < 8; ++kk) {
                int o = (kk * 64 + quad * 16) ^ swz;
                bf16x8 f0 = *(const bf16x8*)(L + rowb0 + o);
                c0 = __builtin_amdgcn_mfma_f32_16x16x32_bf16(afrag[kk], f0, c0, 0, 0, 0);
                bf16x8 f1 = *(const bf16x8*)(L + rowb1 + o);
                c1 = __builtin_amdgcn_mfma_f32_16x16x32_bf16(afrag[kk], f1, c1, 0, 0, 0);
            }
            __builtin_amdgcn_s_setprio(0);
            __builtin_amdgcn_s_barrier();

            // ---- phase 2: kk 8-12, stage slice {5,6} ----
            if (pre_next) stage_part(cur ^ 1, tt + 1, 5, 7);
            __builtin_amdgcn_s_setprio(1);
#pragma unroll
            for (int kk = 8; kk < 13; ++kk) {
                int koffb = kk * 64 + quad * 16;
                int o = (kk < 12) ? (koffb ^ swz) : koffb;   // chunks 48-51 raw
                bf16x8 f0 = *(const bf16x8*)(L + rowb0 + o);
                c0 = __builtin_amdgcn_mfma_f32_16x16x32_bf16(afrag[kk], f0, c0, 0, 0, 0);
                bf16x8 f1 = *(const bf16x8*)(L + rowb1 + o);
                c1 = __builtin_amdgcn_mfma_f32_16x16x32_bf16(afrag[kk], f1, c1, 0, 0, 0);
            }
            __builtin_amdgcn_s_setprio(0);
        } else {
#pragma unroll
            for (int kk = 0; kk < 13; ++kk) {
                int koffb = kk * 64 + quad * 16;
                int o = (kk < 12) ? (koffb ^ swz) : koffb;
                bf16x8 f0 = *(const bf16x8*)(L + rowb0 + o);
                c0 = __builtin_amdgcn_mfma_f32_16x16x32_bf16(afrag[kk], f0, c0, 0, 0, 0);
                bf16x8 f1 = *(const bf16x8*)(L + rowb1 + o);
                c1 = __builtin_amdgcn_mfma_f32_16x16x32_bf16(afrag[kk], f1, c1, 0, 0, 0);
            }
        }

        int t0 = tt * NT;
        float hwv0 = hwb[t0 + lrow];
        float hwv1 = hwb[t0 + 16 + lrow];

        if (t0 + NT > len) {
            if (t0 + lrow >= len) {
                c0[0] = -3.0e38f; c0[1] = -3.0e38f; c0[2] = -3.0e38f; c0[3] = -3.0e38f;
            }
            if (t0 + 16 + lrow >= len) {
                c1[0] = -3.0e38f; c1[1] = -3.0e38f; c1[2] = -3.0e38f; c1[3] = -3.0e38f;
            }
        }

        // online softmax (exp2 domain) with defer-max (T13): skip the rescale
        // when no lane's tile-max exceeds the running max by more than 8
        // (P bounded by 2^8 = 256; l,a have f32 headroom; a/l unchanged).
        float cm[4];
        bool grow = false;
#pragma unroll
        for (int r = 0; r < 4; ++r) {
            cm[r] = fmaxf(c0[r], c1[r]);
            grow = grow || (cm[r] > m_s[r] + 8.0f);
        }
        if (__builtin_amdgcn_ballot_w64(grow) != 0ull) {
#pragma unroll
            for (int r = 0; r < 4; ++r) {
                float mn = fmaxf(m_s[r], cm[r]);
                float alpha = __builtin_amdgcn_exp2f(m_s[r] - mn);
                float p0 = __builtin_amdgcn_exp2f(c0[r] - mn);
                float p1 = __builtin_amdgcn_exp2f(c1[r] - mn);
                l_s[r] = l_s[r] * alpha + p0 + p1;
                a_s[r] = a_s[r] * alpha + p0 * hwv0 + p1 * hwv1;
                m_s[r] = mn;
            }
        } else {
#pragma unroll
            for (int r = 0; r < 4; ++r) {
                float p0 = __builtin_amdgcn_exp2f(c0[r] - m_s[r]);
                float p1 = __builtin_amdgcn_exp2f(c1[r] - m_s[r]);
                l_s[r] = l_s[r] + p0 + p1;
                a_s[r] = a_s[r] + p0 * hwv0 + p1 * hwv1;
            }
        }

        // tile boundary: next tile stages into buf[cur]; all waves must be done
        // reading it, and the 7 prefetch loads must have landed.
        if (PRE) {
            asm volatile("s_waitcnt vmcnt(0)" ::: "memory");
            __builtin_amdgcn_s_barrier();
        } else {
            __syncthreads();
            if (pre_next) stage_f32(cur ^ 1, tt + 1);
            __syncthreads();
        }
    }

    // y_utts reduce + write
#pragma unroll
    for (int r = 0; r < 4; ++r) {
        float m = m_s[r], l = l_s[r], a = a_s[r];
#pragma unroll
        for (int off = 1; off < 16; off <<= 1) {
            float mo = __shfl_xor(m, off, 64);
            float lo = __shfl_xor(l, off, 64);
            float ao = __shfl_xor(a, off, 64);
            float mn = fmaxf(m, mo);
            float f1 = __builtin_amdgcn_exp2f(m - mn);
            float f2 = __builtin_amdgcn_exp2f(mo - mn);
            l = l * f1 + lo * f2;
            a = a * f1 + ao * f2;
            m = mn;
        }
        if (lrow == 0) {
            int v = vbase + wave * 16 + quad * 4 + r;
            out[(size_t)b * NV + v] = a / l + b0;
        }
    }

    // y_acts epilogue: this block owns (b, vbase..vbase+63); wave handles 16 v
    {
        const float4* q4 = (const float4*)(q_ws + (size_t)b * D_);
        float4 qa = q4[lane];
        float4 qb = (lane < 36) ? q4[lane + 64] : make_float4(0.f, 0.f, 0.f, 0.f);
#pragma unroll 1
        for (int ii = 0; ii < 16; ii += 4) {
            int v0 = vbase + wave * 16 + ii;
            float acc[4];
#pragma unroll
            for (int r = 0; r < 4; ++r) {
                const float4* v4 = (const float4*)(Cv + (size_t)(v0 + r) * D_);
                acc[r] = dot4(v4[lane], qa);
                if (lane < 36) acc[r] += dot4(v4[lane + 64], qb);
            }
#pragma unroll
            for (int off = 1; off < 64; off <<= 1) {
#pragma unroll
                for (int r = 0; r < 4; ++r) acc[r] += __shfl_xor(acc[r], off, 64);
            }
            if (lane == 0) {
                float4 o = make_float4(acc[0], acc[1], acc[2], acc[3]);
                *(float4*)(out + (size_t)B_ * NV + (size_t)b * NV + v0) = o;
            }
        }
    }
}

// ---------------------------------------------------------------------------
extern "C" void kernel_launch(void* const* d_in, const int* in_sizes, int n_in,
                              void* d_out, int out_size, void* d_ws, size_t ws_size,
                              hipStream_t stream) {
    const float* H    = (const float*)d_in[0];   // (B,T,D)
    const float* cu   = (const float*)d_in[1];   // (B,D)
    const float* Ca   = (const float*)d_in[2];   // (B,NA,D)
    const float* Cv   = (const float*)d_in[3];   // (NV,1,D)
    const float* W    = (const float*)d_in[4];   // (1,D)
    const float* bs   = (const float*)d_in[5];   // (1,)
    const int*   lens = (const int*)d_in[6];     // (B,)
    float* out = (float*)d_out;                  // f32: y_utts (B,NV) ++ y_acts (B,NV)

    float*  hw   = (float*)d_ws;                        // B*T f32 (256 KB)
    float*  q_ws = hw + (size_t)B_ * T_;                // B*D f32 (200 KB)
    bf16_t* Hbf  = (bf16_t*)(q_ws + (size_t)B_ * D_);   // B*T*416 bf16 (54.5 MB)

    size_t need = ((size_t)B_ * T_ + (size_t)B_ * D_) * sizeof(float)
                + (size_t)B_ * T_ * LDH * sizeof(bf16_t);
    bool pre = (ws_size >= need);

    dim3 pgrid(128 + 2048);
    if (pre) {
        prep_kernel<1><<<pgrid, dim3(256), 0, stream>>>(H, W, cu, Ca, hw, Hbf, q_ws);
        main_kernel<1><<<dim3(2048), dim3(256), 0, stream>>>(H, Hbf, Cv, hw, q_ws, bs, lens, out);
    } else {
        prep_kernel<0><<<pgrid, dim3(256), 0, stream>>>(H, W, cu, Ca, hw, Hbf, q_ws);
        main_kernel<0><<<dim3(2048), dim3(256), 0, stream>>>(H, Hbf, Cv, hw, q_ws, bs, lens, out);
    }
}